// Round 7
// baseline (137.535 us; speedup 1.0000x reference)
//
#include <hip/hip_runtime.h>

#define J 17
#define F 128
#define TB 16          // batches per block (= MFMA N dim)
#define THREADS 512    // 8 waves; wave w owns g band [16w, 16w+16)

typedef __attribute__((ext_vector_type(4))) float f32x4;
typedef __attribute__((ext_vector_type(8))) short bf16x8;   // 8 bf16 in 4 VGPRs

// round-to-nearest-even f32 -> bf16 (prep kernel)
__device__ __forceinline__ unsigned short f2bf(float f) {
    unsigned u = __builtin_bit_cast(unsigned, f);
    u += 0x7fffu + ((u >> 16) & 1u);
    return (unsigned short)(u >> 16);
}
__device__ __forceinline__ float bf2f(unsigned short s) {
    return __builtin_bit_cast(float, (unsigned)s << 16);
}
// pack two f32 (raw bits) -> two bf16, round-half-up: 2 v_add + 1 v_perm
__device__ __forceinline__ unsigned pkbf(unsigned lo, unsigned hi) {
    return __builtin_amdgcn_perm(hi + 0x8000u, lo + 0x8000u, 0x07060302u);
}
__device__ __forceinline__ f32x4 fma4(float a, f32x4 v, f32x4 c) {
    f32x4 av = {a, a, a, a};
    return __builtin_elementwise_fma(av, v, c);
}

// ws: f32[0..288] = A_off (diag zeroed); f32[289..305] = A_diag;
// byte 2048: WT bf16 [2][g=128][k=128]  (WT[mat][g][k] = bf16(W[mat][k][g]))
__global__ void prep(const float* __restrict__ W, const float* __restrict__ adj,
                     const float* __restrict__ adj2, float* __restrict__ wsA,
                     unsigned short* __restrict__ WT) {
    int t = blockIdx.x * 256 + threadIdx.x;
    for (int idx = t; idx < 2 * F * F; idx += 16 * 256) {
        int mat = idx >> 14;
        int rem = idx & 16383;
        int g = rem >> 7, k = rem & 127;
        WT[idx] = f2bf(W[mat * 16384 + k * F + g]);
    }
    if (blockIdx.x == 0) {
        for (int idx = threadIdx.x; idx < J * J; idx += 256) {
            int i = idx / J, j = idx % J;
            float a = 0.5f * (adj[i*J+j] + adj2[i*J+j] + adj[j*J+i] + adj2[j*J+i]);
            wsA[idx] = (i == j) ? 0.0f : a;
            if (i == j) wsA[J * J + i] = a;
        }
    }
}

__global__ __launch_bounds__(THREADS, 2) void mgcn_kernel(
    const float* __restrict__ x, const float* __restrict__ Mw,
    const float* __restrict__ bias, const float* __restrict__ wsA,
    const unsigned short* __restrict__ WT, float* __restrict__ out) {

    // full x tile as bf16: byte = b*4352 + j*256 + k*2, XOR-swizzled by (b&7)<<4
    __shared__ __align__(16) unsigned char xs[TB * J * F * 2];   // 69632 B
    __shared__ __align__(16) unsigned short MsB[J * F];          //  4352 B

    const int tid  = threadIdx.x;
    const int b0   = blockIdx.x * TB;
    const int wave = tid >> 6;
    const int lane = tid & 63;
    const int lrow = lane & 15;           // MFMA 16-index: D col = batch
    const int lq   = lane >> 4;
    const int grow = wave * 16 + lrow;    // A-frag (W^T) row = g
    const int gq   = wave * 16 + lq * 4;  // D reg-quad g base

    // ---- early global loads: W^T fragments (32 VGPRs) + bias quad ----
    bf16x8 wf0[4], wf1[4];
#pragma unroll
    for (int ks = 0; ks < 4; ++ks) {
        const unsigned short* p0 = WT + (size_t)grow * F + ks * 32 + lq * 8;
        wf0[ks] = __builtin_bit_cast(bf16x8, *(const uint4*)p0);
        wf1[ks] = __builtin_bit_cast(bf16x8, *(const uint4*)(p0 + F * F));
    }
    const f32x4 bias4 = *(const f32x4*)(bias + gq);

    // ---- M -> LDS as bf16 ----
    for (int idx = tid; idx < J * F / 4; idx += THREADS) {
        float4 v = ((const float4*)Mw)[idx];
        uint4 u = __builtin_bit_cast(uint4, v);
        uint2 p; p.x = pkbf(u.x, u.y); p.y = pkbf(u.z, u.w);
        *(uint2*)(MsB + idx * 4) = p;
    }

    // ---- stage whole x tile: 17 float4/thread, coalesced; ONE latency exposure ----
    const float4* xg = (const float4*)(x + (size_t)b0 * (J * F));
#pragma unroll
    for (int it = 0; it < (TB * J * F / 4) / THREADS; ++it) {   // 17 iters
        int fi = it * THREADS + tid;
        int b  = fi / (J * F / 4);          // /544
        int r  = fi - b * (J * F / 4);
        int j  = r >> 5;
        int k4 = r & 31;
        float4 v = xg[fi];
        unsigned byte = (unsigned)(b * (J * F * 2) + j * 256 + k4 * 8);
        byte ^= (unsigned)((b & 7) << 4);
        uint4 u = __builtin_bit_cast(uint4, v);
        uint2 p; p.x = pkbf(u.x, u.y); p.y = pkbf(u.z, u.w);
        *(uint2*)(xs + byte) = p;
    }

    f32x4 acc[J];
#pragma unroll
    for (int i = 0; i < J; ++i) acc[i] = bias4;

    const float* __restrict__ Aoff  = wsA;
    const float* __restrict__ Adiag = wsA + J * J;

    __syncthreads();   // the ONLY barrier

    // ---- merged h0/h1 compute: one frag read feeds both MFMAs ----
    const unsigned rbase = (unsigned)(lrow * (J * 256));
    const unsigned swz   = (unsigned)((lrow & 7) << 4);
#pragma unroll
    for (int j = 0; j < J; ++j) {
        f32x4 h0 = {0.f, 0.f, 0.f, 0.f};
        f32x4 h1 = {0.f, 0.f, 0.f, 0.f};
#pragma unroll
        for (int ks = 0; ks < 4; ++ks) {
            unsigned byte = (rbase + (unsigned)(j * 256 + ks * 64 + lq * 16)) ^ swz;
            bf16x8 xf = __builtin_bit_cast(bf16x8, *(const uint4*)(xs + byte));
            h0 = __builtin_amdgcn_mfma_f32_16x16x32_bf16(wf0[ks], xf, h0, 0, 0, 0);
            h1 = __builtin_amdgcn_mfma_f32_16x16x32_bf16(wf1[ks], xf, h1, 0, 0, 0);
        }
        ushort4 m4 = *(const ushort4*)(MsB + j * F + gq);
        f32x4 mj = {bf2f(m4.x), bf2f(m4.y), bf2f(m4.z), bf2f(m4.w)};
        acc[j] = fma4(Adiag[j], mj * h0, acc[j]);
        f32x4 mh1 = mj * h1;
#pragma unroll
        for (int i = 0; i < J; ++i)
            acc[i] = fma4(Aoff[i * J + j], mh1, acc[i]);
    }

    // ---- epilogue: direct f32x4 stores (lane owns out[b0+lrow, i, gq..gq+3]) ----
    float* ob = out + ((size_t)(b0 + lrow) * J) * F + gq;
#pragma unroll
    for (int i = 0; i < J; ++i)
        *(f32x4*)(ob + (size_t)i * F) = acc[i];
}

extern "C" void kernel_launch(void* const* d_in, const int* in_sizes, int n_in,
                              void* d_out, int out_size, void* d_ws, size_t ws_size,
                              hipStream_t stream) {
    const float* x    = (const float*)d_in[0];
    const float* W    = (const float*)d_in[1];
    const float* Mw   = (const float*)d_in[2];
    const float* adj  = (const float*)d_in[3];
    const float* adj2 = (const float*)d_in[4];
    const float* bias = (const float*)d_in[5];
    float* out = (float*)d_out;
    float* wsA = (float*)d_ws;
    unsigned short* WT = (unsigned short*)((char*)d_ws + 2048);

    int Btot = in_sizes[0] / (J * F);   // 16384
    prep<<<16, 256, 0, stream>>>(W, adj, adj2, wsA, WT);
    mgcn_kernel<<<Btot / TB, THREADS, 0, stream>>>(x, Mw, bias, wsA, WT, out);
}

// Round 8
// 87.677 us; speedup vs baseline: 1.5687x; 1.5687x over previous
//
#include <hip/hip_runtime.h>

#define J 17
#define F 128
#define TB 16          // batches per block (= MFMA N dim)
#define THREADS 512    // 8 waves; wave w owns g band [16w, 16w+16)

typedef __attribute__((ext_vector_type(4))) float f32x4;
typedef __attribute__((ext_vector_type(8))) short bf16x8;   // 8 bf16 in 4 VGPRs

// round-to-nearest-even f32 -> bf16 (prep kernel)
__device__ __forceinline__ unsigned short f2bf(float f) {
    unsigned u = __builtin_bit_cast(unsigned, f);
    u += 0x7fffu + ((u >> 16) & 1u);
    return (unsigned short)(u >> 16);
}
// pack two f32 (raw bits) -> two bf16, round-half-up: 2 v_add + 1 v_perm
__device__ __forceinline__ unsigned pkbf(unsigned lo, unsigned hi) {
    return __builtin_amdgcn_perm(hi + 0x8000u, lo + 0x8000u, 0x07060302u);
}
__device__ __forceinline__ f32x4 fma4(float a, f32x4 v, f32x4 c) {
    f32x4 av = {a, a, a, a};
    return __builtin_elementwise_fma(av, v, c);
}

// ws: f32[0..288] = A_off (diag zeroed); f32[289..305] = A_diag;
// byte 2048: WT bf16 [2][g=128][k=128]  (WT[mat][g][k] = bf16(W[mat][k][g]))
__global__ void prep(const float* __restrict__ W, const float* __restrict__ adj,
                     const float* __restrict__ adj2, float* __restrict__ wsA,
                     unsigned short* __restrict__ WT) {
    int t = blockIdx.x * 256 + threadIdx.x;
    for (int idx = t; idx < 2 * F * F; idx += 16 * 256) {
        int mat = idx >> 14;
        int rem = idx & 16383;
        int g = rem >> 7, k = rem & 127;
        WT[idx] = f2bf(W[mat * 16384 + k * F + g]);
    }
    if (blockIdx.x == 0) {
        for (int idx = threadIdx.x; idx < J * J; idx += 256) {
            int i = idx / J, j = idx % J;
            float a = 0.5f * (adj[i*J+j] + adj2[i*J+j] + adj[j*J+i] + adj2[j*J+i]);
            wsA[idx] = (i == j) ? 0.0f : a;
            if (i == j) wsA[J * J + i] = a;
        }
    }
}

__global__ __launch_bounds__(THREADS, 2) void mgcn_kernel(
    const float* __restrict__ x, const float* __restrict__ Mw,
    const float* __restrict__ bias, const float* __restrict__ wsA,
    const unsigned short* __restrict__ WT, float* __restrict__ out) {

    // full x tile as bf16: byte = b*4352 + j*256 + k*2, XOR-swizzled by (b&7)<<4
    __shared__ __align__(16) unsigned char xs[TB * J * F * 2];   // 69632 B
    __shared__ __align__(16) float Ms[J * F];                    //  8704 B

    const int tid  = threadIdx.x;
    const int b0   = blockIdx.x * TB;
    const int wave = tid >> 6;
    const int lane = tid & 63;
    const int lrow = lane & 15;           // MFMA 16-index: D col = batch
    const int lq   = lane >> 4;
    const int grow = wave * 16 + lrow;    // A-frag (W^T) row = g
    const int gq   = wave * 16 + lq * 4;  // D reg-quad g base

    // M -> LDS (f32, vector copy)
    for (int idx = tid; idx < J * F / 4; idx += THREADS)
        ((float4*)Ms)[idx] = ((const float4*)Mw)[idx];

    // ---- stage whole x tile: load-all (17 outstanding), then convert+write ----
    const float4* xg = (const float4*)(x + (size_t)b0 * (J * F));
    float4 sreg[17];
#pragma unroll
    for (int it = 0; it < 17; ++it)
        sreg[it] = xg[it * THREADS + tid];
#pragma unroll
    for (int it = 0; it < 17; ++it) {
        int fi = it * THREADS + tid;
        int b  = fi / (J * F / 4);          // /544
        int r  = fi - b * (J * F / 4);
        int j  = r >> 5;
        int k4 = r & 31;
        unsigned byte = (unsigned)(b * (J * F * 2) + j * 256 + k4 * 8);
        byte ^= (unsigned)((b & 7) << 4);
        uint4 u = __builtin_bit_cast(uint4, sreg[it]);
        uint2 p; p.x = pkbf(u.x, u.y); p.y = pkbf(u.z, u.w);
        *(uint2*)(xs + byte) = p;
    }

    const f32x4 bias4 = *(const f32x4*)(bias + gq);
    f32x4 acc[J];
#pragma unroll
    for (int i = 0; i < J; ++i) acc[i] = bias4;

    const float* __restrict__ Aoff  = wsA;
    const float* __restrict__ Adiag = wsA + J * J;
    const unsigned rbase = (unsigned)(lrow * (J * 256));
    const unsigned swz   = (unsigned)((lrow & 7) << 4);

    __syncthreads();   // the ONLY barrier

    // ---- pass A: diagonal path (wf0 only live) ----
    {
        bf16x8 wf[4];
#pragma unroll
        for (int ks = 0; ks < 4; ++ks)
            wf[ks] = __builtin_bit_cast(bf16x8,
                *(const uint4*)(WT + (size_t)grow * F + ks * 32 + lq * 8));
#pragma unroll
        for (int j = 0; j < J; ++j) {
            f32x4 h0 = {0.f, 0.f, 0.f, 0.f};
#pragma unroll
            for (int ks = 0; ks < 4; ++ks) {
                unsigned byte = (rbase + (unsigned)(j * 256 + ks * 64 + lq * 16)) ^ swz;
                bf16x8 xf = __builtin_bit_cast(bf16x8, *(const uint4*)(xs + byte));
                h0 = __builtin_amdgcn_mfma_f32_16x16x32_bf16(wf[ks], xf, h0, 0, 0, 0);
            }
            f32x4 mj = *(const f32x4*)&Ms[j * F + gq];
            acc[j] = fma4(Adiag[j], mj * h0, acc[j]);
        }
    }

    // ---- pass B: off-diagonal path (wf1 only live) ----
    {
        bf16x8 wf[4];
#pragma unroll
        for (int ks = 0; ks < 4; ++ks)
            wf[ks] = __builtin_bit_cast(bf16x8,
                *(const uint4*)(WT + (size_t)(F * F) + (size_t)grow * F + ks * 32 + lq * 8));
#pragma unroll
        for (int j = 0; j < J; ++j) {
            f32x4 h1 = {0.f, 0.f, 0.f, 0.f};
#pragma unroll
            for (int ks = 0; ks < 4; ++ks) {
                unsigned byte = (rbase + (unsigned)(j * 256 + ks * 64 + lq * 16)) ^ swz;
                bf16x8 xf = __builtin_bit_cast(bf16x8, *(const uint4*)(xs + byte));
                h1 = __builtin_amdgcn_mfma_f32_16x16x32_bf16(wf[ks], xf, h1, 0, 0, 0);
            }
            f32x4 mj  = *(const f32x4*)&Ms[j * F + gq];
            f32x4 mh1 = mj * h1;
#pragma unroll
            for (int i = 0; i < J; ++i)
                acc[i] = fma4(Aoff[i * J + j], mh1, acc[i]);
        }
    }

    // ---- epilogue: direct f32x4 stores (lane owns out[b0+lrow, i, gq..gq+3]) ----
    float* ob = out + ((size_t)(b0 + lrow) * J) * F + gq;
#pragma unroll
    for (int i = 0; i < J; ++i)
        *(f32x4*)(ob + (size_t)i * F) = acc[i];
}

extern "C" void kernel_launch(void* const* d_in, const int* in_sizes, int n_in,
                              void* d_out, int out_size, void* d_ws, size_t ws_size,
                              hipStream_t stream) {
    const float* x    = (const float*)d_in[0];
    const float* W    = (const float*)d_in[1];
    const float* Mw   = (const float*)d_in[2];
    const float* adj  = (const float*)d_in[3];
    const float* adj2 = (const float*)d_in[4];
    const float* bias = (const float*)d_in[5];
    float* out = (float*)d_out;
    float* wsA = (float*)d_ws;
    unsigned short* WT = (unsigned short*)((char*)d_ws + 2048);

    int Btot = in_sizes[0] / (J * F);   // 16384
    prep<<<16, 256, 0, stream>>>(W, adj, adj2, wsA, WT);
    mgcn_kernel<<<Btot / TB, THREADS, 0, stream>>>(x, Mw, bias, wsA, WT, out);
}